// Round 10
// baseline (102.686 us; speedup 1.0000x reference)
//
#include <hip/hip_runtime.h>

#define VV 100000
#define NN 20000
#define KK 32
#define DD 256
#define HH 256
#define BN 16   // nodes per block in fused kernels

typedef __attribute__((ext_vector_type(8))) short bf16x8;
typedef __attribute__((ext_vector_type(4))) float f32x4;
typedef __attribute__((ext_vector_type(2))) float f32x2;
typedef __attribute__((ext_vector_type(4))) uint  u32x4;
typedef __attribute__((ext_vector_type(2))) uint  u32x2;

__device__ __forceinline__ ushort f2bf(float f) {
    // round-to-nearest-even f32 -> bf16
    uint u = __float_as_uint(f);
    return (ushort)((u + 0x7FFFu + ((u >> 16) & 1u)) >> 16);
}
__device__ __forceinline__ float bf2f(ushort u) {
    return __uint_as_float(((uint)u) << 16);
}

// ---------------- Kernel 0a: embed table f32 -> fp8 e4m3 -------------------
// 16 elems/thread: 64 B read (nt, keep L3 for the fp8 table), 16 B write.
__global__ __launch_bounds__(256) void k_conv8(
    const float* __restrict__ E, unsigned char* __restrict__ E8)
{
    const size_t i = ((size_t)blockIdx.x * 256 + threadIdx.x) * 16;
    u32x4 o;
    #pragma unroll
    for (int w = 0; w < 4; ++w) {
        const f32x4 a = __builtin_nontemporal_load((const f32x4*)&E[i + w * 4]);
        int r = 0;
        r = __builtin_amdgcn_cvt_pk_fp8_f32(a.x, a.y, r, false);
        r = __builtin_amdgcn_cvt_pk_fp8_f32(a.z, a.w, r, true);
        o[w] = (uint)r;
    }
    *(u32x4*)&E8[i] = o;
}

// ---------------- Kernel 0b: embed table f32 -> bf16 (fallback tier) -------
__global__ __launch_bounds__(256) void k_conv(
    const float* __restrict__ E, ushort* __restrict__ Eb)
{
    const size_t i = ((size_t)blockIdx.x * 256 + threadIdx.x) * 8;
    const f32x4 a = __builtin_nontemporal_load((const f32x4*)&E[i]);
    const f32x4 b = __builtin_nontemporal_load((const f32x4*)&E[i + 4]);
    bf16x8 v;
    v[0] = (short)f2bf(a.x); v[1] = (short)f2bf(a.y);
    v[2] = (short)f2bf(a.z); v[3] = (short)f2bf(a.w);
    v[4] = (short)f2bf(b.x); v[5] = (short)f2bf(b.y);
    v[6] = (short)f2bf(b.z); v[7] = (short)f2bf(b.w);
    *(bf16x8*)&Eb[i] = v;
}

// ------- Kernel 1: W [D][H] f32 -> W^T [H][D] bf16 -------------------------
__global__ __launch_bounds__(256) void k_prep_w(
    const float* __restrict__ Ws, const float* __restrict__ Wn,
    ushort* __restrict__ WT)   // [2][H][D] bf16
{
    __shared__ float t[64][65];
    const int tid = threadIdx.x;
    const float* src = (blockIdx.z == 0) ? Ws : Wn;
    ushort* dst = WT + (size_t)blockIdx.z * HH * DD;
    const int d0 = blockIdx.x * 64, h0 = blockIdx.y * 64;

    const int hl = tid & 63, dq = tid >> 6;
    #pragma unroll
    for (int i = 0; i < 16; ++i) {
        const int dl = dq * 16 + i;
        t[dl][hl] = src[(size_t)(d0 + dl) * HH + h0 + hl];
    }
    __syncthreads();
    const int dl = tid & 63, hq = tid >> 6;
    #pragma unroll
    for (int i = 0; i < 16; ++i) {
        const int h2 = hq * 16 + i;
        dst[(size_t)(h0 + h2) * DD + d0 + dl] = f2bf(t[dl][h2]);
    }
}

// ------- Kernel 2: fused gather(self f32, nb fp8) + pool + MFMA GEMM -------
// 512 threads = 8 waves, BN=16 nodes/block, grid 1250.
// Phase 1: wave handles nodes {wv, wv+8}; per node one window = 2 f32x4 self
//   loads + 16 paired u32x2 fp8 loads (lo half-wave even nbr, hi odd, ids
//   s-loaded + cndmask). Pool via cvt_pk_f32_fp8 + shfl_xor(32). Store bf16
//   rows to XOR-swizzled LDS (lo half -> As self, hi half -> An pooled).
// Phase 2: wave wv -> half = wv>>2 (self/nb), col-64 block = (wv&3)*64;
//   4 col-tiles x 8 K-steps of mfma 16x16x32 bf16; bias+relu epilogue.
// __launch_bounds__(512,6): VGPR cap ~85 (no spills, round-8 lesson),
// ~3 blocks/CU = 24 waves/CU vs round-6's 34% occupancy.
__global__ __launch_bounds__(512, 6) void k_fused8(
    const float*         __restrict__ Ef,   // f32 embed (self rows)
    const unsigned char* __restrict__ E8,   // fp8 table (neighbor rows)
    const int*           __restrict__ node_ids,
    const int*           __restrict__ nb_ids,
    const ushort*        __restrict__ WT,   // [2][H][D] bf16
    const float*         __restrict__ bias, // [2H]
    float*               __restrict__ out)  // [N][2H]
{
    __shared__ ushort As[BN][DD];
    __shared__ ushort An[BN][DD];
    const int tid  = threadIdx.x;
    const int wv   = tid >> 6;          // 0..7
    const int lane = tid & 63;
    const int sub  = lane >> 5, l31 = lane & 31;
    const int g0   = blockIdx.x * BN;

    // ---- Phase 1: 2 nodes per wave ----
    #pragma unroll
    for (int it = 0; it < 2; ++it) {
        const int n = wv + it * 8;
        const int g = g0 + n;
        const int base = g * KK;
        const uint swz  = ((uint)(n & 7)) << 4;
        const uint boff = (uint)l31 * 16;

        // self row f32, lane covers elems [8*l31, 8*l31+8)
        const int srow = node_ids[g];    // uniform -> s_load
        const f32x4 s0 = *(const f32x4*)&Ef[(size_t)(uint)srow * DD + l31 * 8];
        const f32x4 s1 = *(const f32x4*)&Ef[(size_t)(uint)srow * DD + l31 * 8 + 4];

        // all 32 neighbor rows in one window of 16 paired 8B loads
        u32x2 d[16];
        #pragma unroll
        for (int j = 0; j < 16; ++j) {
            const int rlo = nb_ids[base + 2 * j];       // uniform -> s_load
            const int rhi = nb_ids[base + 2 * j + 1];   // uniform -> s_load
            const int row = sub ? rhi : rlo;            // cndmask
            d[j] = *(const u32x2*)&E8[(size_t)(uint)row * DD + l31 * 8];
        }

        float acc[8];
        #pragma unroll
        for (int e = 0; e < 8; ++e) acc[e] = 0.f;
        #pragma unroll
        for (int j = 0; j < 16; ++j) {
            #pragma unroll
            for (int w = 0; w < 2; ++w) {
                const f32x2 lo = __builtin_amdgcn_cvt_pk_f32_fp8((int)d[j][w], false);
                const f32x2 hi = __builtin_amdgcn_cvt_pk_f32_fp8((int)d[j][w], true);
                acc[w * 4 + 0] += lo.x; acc[w * 4 + 1] += lo.y;
                acc[w * 4 + 2] += hi.x; acc[w * 4 + 3] += hi.y;
            }
        }
        // combine even-row partial (lo half) with odd-row partial (hi half)
        #pragma unroll
        for (int e = 0; e < 8; ++e)
            acc[e] += __shfl_xor(acc[e], 32);

        const float inv = 1.0f / (float)KK;
        bf16x8 nv;
        #pragma unroll
        for (int e = 0; e < 8; ++e)
            nv[e] = (short)f2bf(acc[e] * inv);

        bf16x8 sv;
        sv[0] = (short)f2bf(s0.x); sv[1] = (short)f2bf(s0.y);
        sv[2] = (short)f2bf(s0.z); sv[3] = (short)f2bf(s0.w);
        sv[4] = (short)f2bf(s1.x); sv[5] = (short)f2bf(s1.y);
        sv[6] = (short)f2bf(s1.z); sv[7] = (short)f2bf(s1.w);

        if (sub == 0) {
            *(bf16x8*)((char*)&As[n][0] + (boff ^ swz)) = sv;
        } else {
            *(bf16x8*)((char*)&An[n][0] + (boff ^ swz)) = nv;
        }
    }
    __syncthreads();

    // ---- Phase 2 ----
    const int half = wv >> 2;            // 0 = self, 1 = nb
    const int colo = (wv & 3) * 64;      // 64-col block within half
    const int r16  = lane & 15;          // A row / B col / C col
    const int kg   = lane >> 4;          // k-group (8 bf16 each)
    const uint rswz = ((uint)(r16 & 7)) << 4;
    const char* Arow = (const char*)(half ? &An[r16][0] : &As[r16][0]);

    bf16x8 a[8];
    #pragma unroll
    for (int ks = 0; ks < 8; ++ks) {
        const uint off = (uint)(ks * 64 + kg * 16);
        a[ks] = *(const bf16x8*)(Arow + (off ^ rswz));
    }

    const ushort* Wb = WT + (size_t)half * HH * DD;
    f32x4 accs[4];
    #pragma unroll
    for (int ct = 0; ct < 4; ++ct) {
        const int c = colo + ct * 16 + r16;
        const ushort* Bb = Wb + (size_t)c * DD + kg * 8;
        f32x4 acc = {0.f, 0.f, 0.f, 0.f};
        #pragma unroll
        for (int ks = 0; ks < 8; ++ks) {
            const bf16x8 b = *(const bf16x8*)(Bb + ks * 32);
            acc = __builtin_amdgcn_mfma_f32_16x16x32_bf16(a[ks], b, acc, 0, 0, 0);
        }
        accs[ct] = acc;
    }

    // epilogue: bias + relu; C/D layout col=lane&15, row=(lane>>4)*4+reg
    #pragma unroll
    for (int ct = 0; ct < 4; ++ct) {
        const int cglob = half * HH + colo + ct * 16 + r16;
        const float bv = bias[cglob];
        #pragma unroll
        for (int r = 0; r < 4; ++r) {
            const float v = accs[ct][r] + bv;
            out[(size_t)(g0 + kg * 4 + r) * (2 * HH) + cglob] = v > 0.f ? v : 0.f;
        }
    }
}

// ------- Fallback: fused gather + pool + GEMM (round-6, proven) ------------
template<int EBF16>
__global__ __launch_bounds__(256, 4) void k_fused(
    const float*  __restrict__ Ef,
    const ushort* __restrict__ Eb,
    const int*    __restrict__ node_ids,
    const int*    __restrict__ nb_ids,
    const ushort* __restrict__ WT,       // [2][H][D] bf16
    const float*  __restrict__ bias,
    float*        __restrict__ out)
{
    __shared__ ushort As[BN][DD];
    __shared__ ushort An[BN][DD];
    const int tid  = threadIdx.x;
    const int wave = tid >> 6;
    const int lane = tid & 63;
    const int g0   = blockIdx.x * BN;

    if (EBF16) {
        const int sub = lane >> 5;
        const int l31 = lane & 31;
        const uint boff = (uint)l31 * 16;
        for (int n = wave; n < BN; n += 4) {
            const int g = g0 + n;
            const int base = g * KK;
            const uint swz = ((uint)(n & 7)) << 4;
            const int srow = node_ids[g];
            const bf16x8 sv = *(const bf16x8*)&Eb[((size_t)(uint)srow << 8) + l31 * 8];
            bf16x8 r[16];
            #pragma unroll
            for (int j = 0; j < 16; ++j) {
                const int rlo = nb_ids[base + 2 * j];
                const int rhi = nb_ids[base + 2 * j + 1];
                const int row = sub ? rhi : rlo;
                r[j] = *(const bf16x8*)&Eb[((size_t)(uint)row << 8) + l31 * 8];
            }
            float acc[8];
            #pragma unroll
            for (int e = 0; e < 8; ++e) acc[e] = 0.f;
            #pragma unroll
            for (int j = 0; j < 16; ++j) {
                #pragma unroll
                for (int e = 0; e < 8; ++e)
                    acc[e] += bf2f((ushort)r[j][e]);
            }
            #pragma unroll
            for (int e = 0; e < 8; ++e)
                acc[e] += __shfl_xor(acc[e], 32);
            const float inv = 1.0f / (float)KK;
            bf16x8 nv;
            #pragma unroll
            for (int e = 0; e < 8; ++e)
                nv[e] = (short)f2bf(acc[e] * inv);
            if (sub == 0) {
                *(bf16x8*)((char*)&As[n][0] + (boff ^ swz)) = sv;
            } else {
                *(bf16x8*)((char*)&An[n][0] + (boff ^ swz)) = nv;
            }
        }
    } else {
        for (int n = wave; n < BN; n += 4) {
            const int g = g0 + n;
            const int srow = node_ids[g];
            const uint swz  = ((uint)(n & 7)) << 4;
            const uint boff = (uint)lane * 8;
            const float4 s = *(const float4*)&Ef[(size_t)srow * DD + lane * 4];
            ushort4 sv = make_ushort4(f2bf(s.x), f2bf(s.y), f2bf(s.z), f2bf(s.w));
            float4 acc = make_float4(0.f, 0.f, 0.f, 0.f);
            #pragma unroll
            for (int k0 = 0; k0 < KK; k0 += 8) {
                float4 r[8];
                #pragma unroll
                for (int j = 0; j < 8; ++j) {
                    const int row = nb_ids[g * KK + k0 + j];
                    r[j] = *(const float4*)&Ef[(size_t)row * DD + lane * 4];
                }
                #pragma unroll
                for (int j = 0; j < 8; ++j) {
                    acc.x += r[j].x; acc.y += r[j].y;
                    acc.z += r[j].z; acc.w += r[j].w;
                }
            }
            const float inv = 1.0f / (float)KK;
            const ushort4 nv = make_ushort4(f2bf(acc.x * inv), f2bf(acc.y * inv),
                                            f2bf(acc.z * inv), f2bf(acc.w * inv));
            *(ushort4*)((char*)&As[n][0] + (boff ^ swz)) = sv;
            *(ushort4*)((char*)&An[n][0] + (boff ^ swz)) = nv;
        }
    }
    __syncthreads();

    const int half = wave >> 1;
    const int colq = (wave & 1) * 128;
    const int r16  = lane & 15;
    const int kg   = lane >> 4;
    const uint rswz = ((uint)(r16 & 7)) << 4;
    const char* Arow = (const char*)(half ? &An[r16][0] : &As[r16][0]);

    bf16x8 a[8];
    #pragma unroll
    for (int ks = 0; ks < 8; ++ks) {
        const uint off = (uint)(ks * 64 + kg * 16);
        a[ks] = *(const bf16x8*)(Arow + (off ^ rswz));
    }

    const ushort* Wb = WT + (size_t)half * HH * DD;
    f32x4 accs[8];
    #pragma unroll
    for (int ct = 0; ct < 8; ++ct) {
        const int c = colq + ct * 16 + r16;
        const ushort* Bb = Wb + (size_t)c * DD + kg * 8;
        f32x4 acc = {0.f, 0.f, 0.f, 0.f};
        #pragma unroll
        for (int ks = 0; ks < 8; ++ks) {
            const bf16x8 b = *(const bf16x8*)(Bb + ks * 32);
            acc = __builtin_amdgcn_mfma_f32_16x16x32_bf16(a[ks], b, acc, 0, 0, 0);
        }
        accs[ct] = acc;
    }

    #pragma unroll
    for (int ct = 0; ct < 8; ++ct) {
        const int cglob = half * HH + colq + ct * 16 + r16;
        const float bv = bias[cglob];
        #pragma unroll
        for (int r = 0; r < 4; ++r) {
            const float v = accs[ct][r] + bv;
            out[(size_t)(g0 + kg * 4 + r) * (2 * HH) + cglob] = v > 0.f ? v : 0.f;
        }
    }
}

// ---------------- Ultimate fallback (round-1 fused fp32 kernel) ------------
__global__ __launch_bounds__(256, 4) void hetegraph_fused_kernel(
    const float* __restrict__ embed, const int* __restrict__ node_ids,
    const int* __restrict__ nb_ids, const float* __restrict__ Ws,
    const float* __restrict__ Wn, const float* __restrict__ bias,
    float* __restrict__ out)
{
    __shared__ float As[BN][DD];
    __shared__ float An[BN][DD];
    const int tid = threadIdx.x, wave = tid >> 6, lane = tid & 63;
    const int g0 = blockIdx.x * BN;
    for (int n = wave; n < BN; n += 4) {
        const int g = g0 + n;
        const int self_row = node_ids[g];
        const float4 s = *(const float4*)&embed[(size_t)self_row * DD + lane * 4];
        float4 acc = make_float4(0.f, 0.f, 0.f, 0.f);
        for (int k0 = 0; k0 < KK; k0 += 8) {
            float4 r[8];
            #pragma unroll
            for (int j = 0; j < 8; ++j) {
                const int row = nb_ids[g * KK + k0 + j];
                r[j] = *(const float4*)&embed[(size_t)row * DD + lane * 4];
            }
            #pragma unroll
            for (int j = 0; j < 8; ++j) {
                acc.x += r[j].x; acc.y += r[j].y; acc.z += r[j].z; acc.w += r[j].w;
            }
        }
        const float inv = 1.0f / (float)KK;
        *(float4*)&As[n][lane * 4] = s;
        float4 m = make_float4(acc.x * inv, acc.y * inv, acc.z * inv, acc.w * inv);
        *(float4*)&An[n][lane * 4] = m;
    }
    __syncthreads();
    const int h = tid;
    {
        float acc[BN];
        #pragma unroll
        for (int n = 0; n < BN; ++n) acc[n] = 0.f;
        for (int d0 = 0; d0 < DD; d0 += 4) {
            const float w0 = Ws[(d0+0)*HH+h], w1 = Ws[(d0+1)*HH+h];
            const float w2 = Ws[(d0+2)*HH+h], w3 = Ws[(d0+3)*HH+h];
            #pragma unroll
            for (int n = 0; n < BN; ++n) {
                const float4 a = *(const float4*)&As[n][d0];
                acc[n] = fmaf(a.x,w0,acc[n]); acc[n] = fmaf(a.y,w1,acc[n]);
                acc[n] = fmaf(a.z,w2,acc[n]); acc[n] = fmaf(a.w,w3,acc[n]);
            }
        }
        const float b = bias[h];
        #pragma unroll
        for (int n = 0; n < BN; ++n) {
            const float v = acc[n] + b;
            out[(size_t)(g0+n)*(2*HH) + h] = v > 0.f ? v : 0.f;
        }
    }
    {
        float acc[BN];
        #pragma unroll
        for (int n = 0; n < BN; ++n) acc[n] = 0.f;
        for (int d0 = 0; d0 < DD; d0 += 4) {
            const float w0 = Wn[(d0+0)*HH+h], w1 = Wn[(d0+1)*HH+h];
            const float w2 = Wn[(d0+2)*HH+h], w3 = Wn[(d0+3)*HH+h];
            #pragma unroll
            for (int n = 0; n < BN; ++n) {
                const float4 a = *(const float4*)&An[n][d0];
                acc[n] = fmaf(a.x,w0,acc[n]); acc[n] = fmaf(a.y,w1,acc[n]);
                acc[n] = fmaf(a.z,w2,acc[n]); acc[n] = fmaf(a.w,w3,acc[n]);
            }
        }
        const float b = bias[HH + h];
        #pragma unroll
        for (int n = 0; n < BN; ++n) {
            const float v = acc[n] + b;
            out[(size_t)(g0+n)*(2*HH) + HH + h] = v > 0.f ? v : 0.f;
        }
    }
}

extern "C" void kernel_launch(void* const* d_in, const int* in_sizes, int n_in,
                              void* d_out, int out_size, void* d_ws, size_t ws_size,
                              hipStream_t stream) {
    const float* embed    = (const float*)d_in[0];
    const int*   node_ids = (const int*)d_in[1];
    const int*   nb_ids   = (const int*)d_in[2];
    const float* Ws       = (const float*)d_in[3];
    const float* Wn       = (const float*)d_in[4];
    const float* bias     = (const float*)d_in[5];
    float*       out      = (float*)d_out;

    const size_t e8_bytes = (size_t)VV * DD;                    // 25.6 MB
    const size_t eb_bytes = (size_t)VV * DD * sizeof(ushort);   // 51.2 MB
    const size_t wt_bytes = 2ull * HH * DD * sizeof(ushort);    // 256 KB

    if (ws_size >= e8_bytes + wt_bytes) {
        unsigned char* E8 = (unsigned char*)d_ws;
        ushort*        WT = (ushort*)((char*)d_ws + e8_bytes);
        k_conv8<<<dim3(VV * DD / 4096), dim3(256), 0, stream>>>(embed, E8);
        k_prep_w<<<dim3(DD / 64, HH / 64, 2), dim3(256), 0, stream>>>(Ws, Wn, WT);
        k_fused8<<<dim3(NN / BN), dim3(512), 0, stream>>>(
            embed, E8, node_ids, nb_ids, WT, bias, out);
    } else if (ws_size >= eb_bytes + wt_bytes) {
        ushort* Eb = (ushort*)d_ws;
        ushort* WT = (ushort*)((char*)d_ws + eb_bytes);
        k_conv<<<dim3(VV * DD / 2048), dim3(256), 0, stream>>>(embed, Eb);
        k_prep_w<<<dim3(DD / 64, HH / 64, 2), dim3(256), 0, stream>>>(Ws, Wn, WT);
        k_fused<1><<<dim3(NN / BN), dim3(256), 0, stream>>>(
            nullptr, Eb, node_ids, nb_ids, WT, bias, out);
    } else if (ws_size >= wt_bytes) {
        ushort* WT = (ushort*)d_ws;
        k_prep_w<<<dim3(DD / 64, HH / 64, 2), dim3(256), 0, stream>>>(Ws, Wn, WT);
        k_fused<0><<<dim3(NN / BN), dim3(256), 0, stream>>>(
            embed, nullptr, node_ids, nb_ids, WT, bias, out);
    } else {
        hetegraph_fused_kernel<<<dim3(NN / BN), dim3(256), 0, stream>>>(
            embed, node_ids, nb_ids, Ws, Wn, bias, out);
    }
}

// Round 11
// 93.283 us; speedup vs baseline: 1.1008x; 1.1008x over previous
//
#include <hip/hip_runtime.h>

#define VV 100000
#define NN 20000
#define KK 32
#define DD 256
#define HH 256
#define BN 16   // nodes per block in fallback fused kernels

typedef __attribute__((ext_vector_type(8))) short bf16x8;
typedef __attribute__((ext_vector_type(4))) float f32x4;
typedef __attribute__((ext_vector_type(2))) float f32x2;
typedef __attribute__((ext_vector_type(4))) uint  u32x4;
typedef __attribute__((ext_vector_type(2))) uint  u32x2;

__device__ __forceinline__ ushort f2bf(float f) {
    // round-to-nearest-even f32 -> bf16
    uint u = __float_as_uint(f);
    return (ushort)((u + 0x7FFFu + ((u >> 16) & 1u)) >> 16);
}
__device__ __forceinline__ float bf2f(ushort u) {
    return __uint_as_float(((uint)u) << 16);
}

// ---------------- Kernel 0a: embed table f32 -> fp8 e4m3 -------------------
// 16 elems/thread: 64 B read (nt, keep L3 for the fp8 table), 16 B write.
__global__ __launch_bounds__(256) void k_conv8(
    const float* __restrict__ E, unsigned char* __restrict__ E8)
{
    const size_t i = ((size_t)blockIdx.x * 256 + threadIdx.x) * 16;
    u32x4 o;
    #pragma unroll
    for (int w = 0; w < 4; ++w) {
        const f32x4 a = __builtin_nontemporal_load((const f32x4*)&E[i + w * 4]);
        int r = 0;
        r = __builtin_amdgcn_cvt_pk_fp8_f32(a.x, a.y, r, false);
        r = __builtin_amdgcn_cvt_pk_fp8_f32(a.z, a.w, r, true);
        o[w] = (uint)r;
    }
    *(u32x4*)&E8[i] = o;
}

// ---------------- Kernel 0b: embed table f32 -> bf16 (fallback tier) -------
__global__ __launch_bounds__(256) void k_conv(
    const float* __restrict__ E, ushort* __restrict__ Eb)
{
    const size_t i = ((size_t)blockIdx.x * 256 + threadIdx.x) * 8;
    const f32x4 a = __builtin_nontemporal_load((const f32x4*)&E[i]);
    const f32x4 b = __builtin_nontemporal_load((const f32x4*)&E[i + 4]);
    bf16x8 v;
    v[0] = (short)f2bf(a.x); v[1] = (short)f2bf(a.y);
    v[2] = (short)f2bf(a.z); v[3] = (short)f2bf(a.w);
    v[4] = (short)f2bf(b.x); v[5] = (short)f2bf(b.y);
    v[6] = (short)f2bf(b.z); v[7] = (short)f2bf(b.w);
    *(bf16x8*)&Eb[i] = v;
}

// ------- Kernel 1b: W [D][H] f32 -> fragment-major WTf [2][16][8][64][8] ---
// Slot (h, t, ks, lane): lane holds W[k = ks*32 + (lane>>4)*8 + e][t*16 + (lane&15)]
__global__ __launch_bounds__(256) void k_prep_wf(
    const float* __restrict__ Ws, const float* __restrict__ Wn,
    ushort* __restrict__ WTf)
{
    __shared__ float t[256][17];
    const int tid = threadIdx.x;
    const int h   = blockIdx.y;        // half (0=self,1=nb)
    const int tt  = blockIdx.x;        // col tile
    const float* src = h ? Wn : Ws;
    const int h0 = tt * 16;
    const int c = tid & 15, dr = tid >> 4;
    #pragma unroll
    for (int s = 0; s < 16; ++s) {
        const int d = s * 16 + dr;
        t[d][c] = src[(size_t)d * HH + h0 + c];
    }
    __syncthreads();
    const int fl = tid & 63, w = tid >> 6;
    const int r16 = fl & 15, kg = fl >> 4;
    #pragma unroll
    for (int p = 0; p < 2; ++p) {
        const int ks = w + p * 4;
        bf16x8 v;
        #pragma unroll
        for (int e = 0; e < 8; ++e)
            v[e] = (short)f2bf(t[ks * 32 + kg * 8 + e][r16]);
        *(bf16x8*)&WTf[(((size_t)(h * 16 + tt) * 8 + ks) * 64 + fl) * 8] = v;
    }
}

// ------- Kernel 1: W [D][H] f32 -> W^T [H][D] bf16 (for fallback tiers) ----
__global__ __launch_bounds__(256) void k_prep_w(
    const float* __restrict__ Ws, const float* __restrict__ Wn,
    ushort* __restrict__ WT)   // [2][H][D] bf16
{
    __shared__ float t[64][65];
    const int tid = threadIdx.x;
    const float* src = (blockIdx.z == 0) ? Ws : Wn;
    ushort* dst = WT + (size_t)blockIdx.z * HH * DD;
    const int d0 = blockIdx.x * 64, h0 = blockIdx.y * 64;

    const int hl = tid & 63, dq = tid >> 6;
    #pragma unroll
    for (int i = 0; i < 16; ++i) {
        const int dl = dq * 16 + i;
        t[dl][hl] = src[(size_t)(d0 + dl) * HH + h0 + hl];
    }
    __syncthreads();
    const int dl = tid & 63, hq = tid >> 6;
    #pragma unroll
    for (int i = 0; i < 16; ++i) {
        const int h2 = hq * 16 + i;
        dst[(size_t)(h0 + h2) * DD + d0 + dl] = f2bf(t[dl][h2]);
    }
}

// ------- Kernel 2: gather(self f32, nb fp8) + mean-pool -> A frag-major ----
// One node per wave, half-wave pairing (round-6/7 proven addressing):
// fp8 row = 256 B = 32 lanes x 8 B. lo half-wave = even neighbors, hi = odd,
// ids s-loaded (wave-uniform) + cndmask. One window: self (2 f32x4 loads) +
// 16 u32x2 neighbor loads = all 33 rows in flight. ~70 VGPR live.
// __launch_bounds__(256,6): VGPR cap ~84 (> ~70 needed, window intact,
// round-8 spill lesson respected) -> 24 waves/CU vs 16 at (256,4).
// A layout: [tile][half][ks][64][8]; half 0 = self, half 1 = pooled.
__global__ __launch_bounds__(256, 6) void k_gather8(
    const float*         __restrict__ Ef,   // f32 embed (self rows)
    const unsigned char* __restrict__ E8,   // fp8 table (neighbor rows)
    const int*           __restrict__ node_ids,
    const int*           __restrict__ nb_ids,
    ushort*              __restrict__ A)
{
    const int wv   = threadIdx.x >> 6;
    const int lane = threadIdx.x & 63;
    const int sub  = lane >> 5, l31 = lane & 31;
    const int g    = blockIdx.x * 4 + wv;
    const int base = g * KK;

    // self row, f32, full precision: lane covers elements [8*l31, 8*l31+8)
    const int srow = node_ids[g];            // uniform -> s_load
    const f32x4 s0 = *(const f32x4*)&Ef[(size_t)(uint)srow * DD + l31 * 8];
    const f32x4 s1 = *(const f32x4*)&Ef[(size_t)(uint)srow * DD + l31 * 8 + 4];

    // all 32 neighbor rows in one window of 16 paired 8B loads
    u32x2 d[16];
    #pragma unroll
    for (int j = 0; j < 16; ++j) {
        const int rlo = nb_ids[base + 2 * j];       // uniform -> s_load
        const int rhi = nb_ids[base + 2 * j + 1];   // uniform -> s_load
        const int row = sub ? rhi : rlo;            // cndmask
        d[j] = *(const u32x2*)&E8[(size_t)(uint)row * DD + l31 * 8];
    }

    // pool: lane accumulates its 8-element slice across 16 rows
    float acc[8];
    #pragma unroll
    for (int e = 0; e < 8; ++e) acc[e] = 0.f;
    #pragma unroll
    for (int j = 0; j < 16; ++j) {
        #pragma unroll
        for (int w = 0; w < 2; ++w) {
            const f32x2 lo = __builtin_amdgcn_cvt_pk_f32_fp8((int)d[j][w], false);
            const f32x2 hi = __builtin_amdgcn_cvt_pk_f32_fp8((int)d[j][w], true);
            acc[w * 4 + 0] += lo.x; acc[w * 4 + 1] += lo.y;
            acc[w * 4 + 2] += hi.x; acc[w * 4 + 3] += hi.y;
        }
    }
    // combine even-row partial (lo half) with odd-row partial (hi half)
    #pragma unroll
    for (int e = 0; e < 8; ++e)
        acc[e] += __shfl_xor(acc[e], 32);

    const float inv = 1.0f / (float)KK;
    bf16x8 nv;
    #pragma unroll
    for (int e = 0; e < 8; ++e)
        nv[e] = (short)f2bf(acc[e] * inv);

    bf16x8 sv;
    sv[0] = (short)f2bf(s0.x); sv[1] = (short)f2bf(s0.y);
    sv[2] = (short)f2bf(s0.z); sv[3] = (short)f2bf(s0.w);
    sv[4] = (short)f2bf(s1.x); sv[5] = (short)f2bf(s1.y);
    sv[6] = (short)f2bf(s1.z); sv[7] = (short)f2bf(s1.w);

    // lo half stores self (half 0), hi half stores pooled (half 1);
    // fragment slot: ks = l31>>2, kg = l31&3, row-in-tile rr
    const int tile = g >> 4, rr = g & 15;
    const int ks = l31 >> 2, kgw = l31 & 3;
    const size_t dst = (((size_t)(tile * 2 + sub) * 8 + ks) * 64 + kgw * 16 + rr) * 8;
    *(bf16x8*)&A[dst] = sub ? nv : sv;
}

// ------- Kernel 3: GEMM, fully-coalesced fragment loads --------------------
__global__ __launch_bounds__(256, 4) void k_gemmf(
    const ushort* __restrict__ A,     // [tiles][2][8][64][8]
    const ushort* __restrict__ WTf,   // [2][16][8][64][8]
    const float*  __restrict__ bias,  // [2H]
    float*        __restrict__ out)   // [N][2H]
{
    const int wv   = __builtin_amdgcn_readfirstlane((int)(threadIdx.x >> 6));
    const int lane = threadIdx.x & 63;
    const int tile = blockIdx.x;
    const int half = wv >> 1, qt = wv & 1;
    const int r16 = lane & 15, kg = lane >> 4;

    bf16x8 a[8];
    #pragma unroll
    for (int ks = 0; ks < 8; ++ks)
        a[ks] = *(const bf16x8*)&A[(((size_t)(tile * 2 + half) * 8 + ks) * 64 + lane) * 8];

    f32x4 accs[8];
    #pragma unroll
    for (int ct = 0; ct < 8; ++ct) {
        const int t = qt * 8 + ct;
        f32x4 acc = {0.f, 0.f, 0.f, 0.f};
        #pragma unroll
        for (int ks = 0; ks < 8; ++ks) {
            const bf16x8 b = *(const bf16x8*)&WTf[(((size_t)(half * 16 + t) * 8 + ks) * 64 + lane) * 8];
            acc = __builtin_amdgcn_mfma_f32_16x16x32_bf16(a[ks], b, acc, 0, 0, 0);
        }
        accs[ct] = acc;
    }

    #pragma unroll
    for (int ct = 0; ct < 8; ++ct) {
        const int cglob = half * HH + (qt * 8 + ct) * 16 + r16;
        const float bv = bias[cglob];
        #pragma unroll
        for (int r = 0; r < 4; ++r) {
            const float v = accs[ct][r] + bv;
            out[(size_t)(tile * 16 + kg * 4 + r) * (2 * HH) + cglob] = v > 0.f ? v : 0.f;
        }
    }
}

// ------- Fallback: fused gather + pool + GEMM (round-6, proven) ------------
template<int EBF16>
__global__ __launch_bounds__(256, 4) void k_fused(
    const float*  __restrict__ Ef,
    const ushort* __restrict__ Eb,
    const int*    __restrict__ node_ids,
    const int*    __restrict__ nb_ids,
    const ushort* __restrict__ WT,       // [2][H][D] bf16
    const float*  __restrict__ bias,
    float*        __restrict__ out)
{
    __shared__ ushort As[BN][DD];
    __shared__ ushort An[BN][DD];
    const int tid  = threadIdx.x;
    const int wave = tid >> 6;
    const int lane = tid & 63;
    const int g0   = blockIdx.x * BN;

    if (EBF16) {
        const int sub = lane >> 5;
        const int l31 = lane & 31;
        const uint boff = (uint)l31 * 16;
        for (int n = wave; n < BN; n += 4) {
            const int g = g0 + n;
            const int base = g * KK;
            const uint swz = ((uint)(n & 7)) << 4;
            const int srow = node_ids[g];
            const bf16x8 sv = *(const bf16x8*)&Eb[((size_t)(uint)srow << 8) + l31 * 8];
            bf16x8 r[16];
            #pragma unroll
            for (int j = 0; j < 16; ++j) {
                const int rlo = nb_ids[base + 2 * j];
                const int rhi = nb_ids[base + 2 * j + 1];
                const int row = sub ? rhi : rlo;
                r[j] = *(const bf16x8*)&Eb[((size_t)(uint)row << 8) + l31 * 8];
            }
            float acc[8];
            #pragma unroll
            for (int e = 0; e < 8; ++e) acc[e] = 0.f;
            #pragma unroll
            for (int j = 0; j < 16; ++j) {
                #pragma unroll
                for (int e = 0; e < 8; ++e)
                    acc[e] += bf2f((ushort)r[j][e]);
            }
            #pragma unroll
            for (int e = 0; e < 8; ++e)
                acc[e] += __shfl_xor(acc[e], 32);
            const float inv = 1.0f / (float)KK;
            bf16x8 nv;
            #pragma unroll
            for (int e = 0; e < 8; ++e)
                nv[e] = (short)f2bf(acc[e] * inv);
            if (sub == 0) {
                *(bf16x8*)((char*)&As[n][0] + (boff ^ swz)) = sv;
            } else {
                *(bf16x8*)((char*)&An[n][0] + (boff ^ swz)) = nv;
            }
        }
    } else {
        for (int n = wave; n < BN; n += 4) {
            const int g = g0 + n;
            const int srow = node_ids[g];
            const uint swz  = ((uint)(n & 7)) << 4;
            const uint boff = (uint)lane * 8;
            const float4 s = *(const float4*)&Ef[(size_t)srow * DD + lane * 4];
            ushort4 sv = make_ushort4(f2bf(s.x), f2bf(s.y), f2bf(s.z), f2bf(s.w));
            float4 acc = make_float4(0.f, 0.f, 0.f, 0.f);
            #pragma unroll
            for (int k0 = 0; k0 < KK; k0 += 8) {
                float4 r[8];
                #pragma unroll
                for (int j = 0; j < 8; ++j) {
                    const int row = nb_ids[g * KK + k0 + j];
                    r[j] = *(const float4*)&Ef[(size_t)row * DD + lane * 4];
                }
                #pragma unroll
                for (int j = 0; j < 8; ++j) {
                    acc.x += r[j].x; acc.y += r[j].y;
                    acc.z += r[j].z; acc.w += r[j].w;
                }
            }
            const float inv = 1.0f / (float)KK;
            const ushort4 nv = make_ushort4(f2bf(acc.x * inv), f2bf(acc.y * inv),
                                            f2bf(acc.z * inv), f2bf(acc.w * inv));
            *(ushort4*)((char*)&As[n][0] + (boff ^ swz)) = sv;
            *(ushort4*)((char*)&An[n][0] + (boff ^ swz)) = nv;
        }
    }
    __syncthreads();

    const int half = wave >> 1;
    const int colq = (wave & 1) * 128;
    const int r16  = lane & 15;
    const int kg   = lane >> 4;
    const uint rswz = ((uint)(r16 & 7)) << 4;
    const char* Arow = (const char*)(half ? &An[r16][0] : &As[r16][0]);

    bf16x8 a[8];
    #pragma unroll
    for (int ks = 0; ks < 8; ++ks) {
        const uint off = (uint)(ks * 64 + kg * 16);
        a[ks] = *(const bf16x8*)(Arow + (off ^ rswz));
    }

    const ushort* Wb = WT + (size_t)half * HH * DD;
    f32x4 accs[8];
    #pragma unroll
    for (int ct = 0; ct < 8; ++ct) {
        const int c = colq + ct * 16 + r16;
        const ushort* Bb = Wb + (size_t)c * DD + kg * 8;
        f32x4 acc = {0.f, 0.f, 0.f, 0.f};
        #pragma unroll
        for (int ks = 0; ks < 8; ++ks) {
            const bf16x8 b = *(const bf16x8*)(Bb + ks * 32);
            acc = __builtin_amdgcn_mfma_f32_16x16x32_bf16(a[ks], b, acc, 0, 0, 0);
        }
        accs[ct] = acc;
    }

    #pragma unroll
    for (int ct = 0; ct < 8; ++ct) {
        const int cglob = half * HH + colq + ct * 16 + r16;
        const float bv = bias[cglob];
        #pragma unroll
        for (int r = 0; r < 4; ++r) {
            const float v = accs[ct][r] + bv;
            out[(size_t)(g0 + kg * 4 + r) * (2 * HH) + cglob] = v > 0.f ? v : 0.f;
        }
    }
}

// ---------------- Ultimate fallback (round-1 fused fp32 kernel) ------------
__global__ __launch_bounds__(256, 4) void hetegraph_fused_kernel(
    const float* __restrict__ embed, const int* __restrict__ node_ids,
    const int* __restrict__ nb_ids, const float* __restrict__ Ws,
    const float* __restrict__ Wn, const float* __restrict__ bias,
    float* __restrict__ out)
{
    __shared__ float As[BN][DD];
    __shared__ float An[BN][DD];
    const int tid = threadIdx.x, wave = tid >> 6, lane = tid & 63;
    const int g0 = blockIdx.x * BN;
    for (int n = wave; n < BN; n += 4) {
        const int g = g0 + n;
        const int self_row = node_ids[g];
        const float4 s = *(const float4*)&embed[(size_t)self_row * DD + lane * 4];
        float4 acc = make_float4(0.f, 0.f, 0.f, 0.f);
        for (int k0 = 0; k0 < KK; k0 += 8) {
            float4 r[8];
            #pragma unroll
            for (int j = 0; j < 8; ++j) {
                const int row = nb_ids[g * KK + k0 + j];
                r[j] = *(const float4*)&embed[(size_t)row * DD + lane * 4];
            }
            #pragma unroll
            for (int j = 0; j < 8; ++j) {
                acc.x += r[j].x; acc.y += r[j].y; acc.z += r[j].z; acc.w += r[j].w;
            }
        }
        const float inv = 1.0f / (float)KK;
        *(float4*)&As[n][lane * 4] = s;
        float4 m = make_float4(acc.x * inv, acc.y * inv, acc.z * inv, acc.w * inv);
        *(float4*)&An[n][lane * 4] = m;
    }
    __syncthreads();
    const int h = tid;
    {
        float acc[BN];
        #pragma unroll
        for (int n = 0; n < BN; ++n) acc[n] = 0.f;
        for (int d0 = 0; d0 < DD; d0 += 4) {
            const float w0 = Ws[(d0+0)*HH+h], w1 = Ws[(d0+1)*HH+h];
            const float w2 = Ws[(d0+2)*HH+h], w3 = Ws[(d0+3)*HH+h];
            #pragma unroll
            for (int n = 0; n < BN; ++n) {
                const float4 a = *(const float4*)&As[n][d0];
                acc[n] = fmaf(a.x,w0,acc[n]); acc[n] = fmaf(a.y,w1,acc[n]);
                acc[n] = fmaf(a.z,w2,acc[n]); acc[n] = fmaf(a.w,w3,acc[n]);
            }
        }
        const float b = bias[h];
        #pragma unroll
        for (int n = 0; n < BN; ++n) {
            const float v = acc[n] + b;
            out[(size_t)(g0+n)*(2*HH) + h] = v > 0.f ? v : 0.f;
        }
    }
    {
        float acc[BN];
        #pragma unroll
        for (int n = 0; n < BN; ++n) acc[n] = 0.f;
        for (int d0 = 0; d0 < DD; d0 += 4) {
            const float w0 = Wn[(d0+0)*HH+h], w1 = Wn[(d0+1)*HH+h];
            const float w2 = Wn[(d0+2)*HH+h], w3 = Wn[(d0+3)*HH+h];
            #pragma unroll
            for (int n = 0; n < BN; ++n) {
                const float4 a = *(const float4*)&An[n][d0];
                acc[n] = fmaf(a.x,w0,acc[n]); acc[n] = fmaf(a.y,w1,acc[n]);
                acc[n] = fmaf(a.z,w2,acc[n]); acc[n] = fmaf(a.w,w3,acc[n]);
            }
        }
        const float b = bias[HH + h];
        #pragma unroll
        for (int n = 0; n < BN; ++n) {
            const float v = acc[n] + b;
            out[(size_t)(g0+n)*(2*HH) + HH + h] = v > 0.f ? v : 0.f;
        }
    }
}

extern "C" void kernel_launch(void* const* d_in, const int* in_sizes, int n_in,
                              void* d_out, int out_size, void* d_ws, size_t ws_size,
                              hipStream_t stream) {
    const float* embed    = (const float*)d_in[0];
    const int*   node_ids = (const int*)d_in[1];
    const int*   nb_ids   = (const int*)d_in[2];
    const float* Ws       = (const float*)d_in[3];
    const float* Wn       = (const float*)d_in[4];
    const float* bias     = (const float*)d_in[5];
    float*       out      = (float*)d_out;

    const size_t e8_bytes  = (size_t)VV * DD;                              // 25.6 MB
    const size_t eb_bytes  = (size_t)VV * DD * sizeof(ushort);             // 51.2 MB
    const size_t wtf_bytes = 2ull * 16 * 8 * 64 * 8 * sizeof(ushort);      // 256 KB
    const size_t af_bytes  = (size_t)(NN / 16) * 2 * 8 * 64 * 8 * sizeof(ushort); // 20.48 MB
    const size_t wt_bytes  = 2ull * HH * DD * sizeof(ushort);              // 256 KB

    if (ws_size >= e8_bytes + wtf_bytes + af_bytes) {
        unsigned char* E8  = (unsigned char*)d_ws;
        ushort*        WTf = (ushort*)((char*)d_ws + e8_bytes);
        ushort*        Af  = (ushort*)((char*)d_ws + e8_bytes + wtf_bytes);
        k_prep_wf<<<dim3(16, 2), dim3(256), 0, stream>>>(Ws, Wn, WTf);
        k_conv8<<<dim3(VV * DD / 4096), dim3(256), 0, stream>>>(embed, E8);
        k_gather8<<<dim3(NN / 4), dim3(256), 0, stream>>>(embed, E8, node_ids, nb_ids, Af);
        k_gemmf<<<dim3(NN / 16), dim3(256), 0, stream>>>(Af, WTf, bias, out);
    } else if (ws_size >= eb_bytes + wt_bytes) {
        ushort* Eb = (ushort*)d_ws;
        ushort* WT = (ushort*)((char*)d_ws + eb_bytes);
        k_conv<<<dim3(VV * DD / 2048), dim3(256), 0, stream>>>(embed, Eb);
        k_prep_w<<<dim3(DD / 64, HH / 64, 2), dim3(256), 0, stream>>>(Ws, Wn, WT);
        k_fused<1><<<dim3(NN / BN), dim3(256), 0, stream>>>(
            nullptr, Eb, node_ids, nb_ids, WT, bias, out);
    } else if (ws_size >= wt_bytes) {
        ushort* WT = (ushort*)d_ws;
        k_prep_w<<<dim3(DD / 64, HH / 64, 2), dim3(256), 0, stream>>>(Ws, Wn, WT);
        k_fused<0><<<dim3(NN / BN), dim3(256), 0, stream>>>(
            embed, nullptr, node_ids, nb_ids, WT, bias, out);
    } else {
        hetegraph_fused_kernel<<<dim3(NN / BN), dim3(256), 0, stream>>>(
            embed, node_ids, nb_ids, Ws, Wn, bias, out);
    }
}